// Round 14
// baseline (244.337 us; speedup 1.0000x reference)
//
#include <hip/hip_runtime.h>
#include <math.h>

#define N_NODES 50000
#define N_EDGES 400000
#define N_TOT   450000   /* edges + self-loops */
#define NEG 0.2f
#define CAP 64           /* edge bucket capacity; deg = Poisson(8)+1, max over dataset ~27 */

typedef __attribute__((ext_vector_type(8))) short bf16x8;
typedef __attribute__((ext_vector_type(4))) float f32x4;

__device__ __forceinline__ float lrelu(float x) { return x > 0.f ? x : NEG * x; }

__device__ __forceinline__ unsigned short f2bf(float f) {
    unsigned u = __float_as_uint(f);
    unsigned r = u + 0x7FFFu + ((u >> 16) & 1u);   /* RNE */
    return (unsigned short)(r >> 16);
}
__device__ __forceinline__ float bf2f(unsigned short h) {
    return __uint_as_float(((unsigned)h) << 16);
}

/* ---------------- init: weight prep (W1/W2 hi, W1a hi+lo) + cursor zero ---------------- */
__global__ void k_init(const float* __restrict__ W1, unsigned short* W1hiT,
                       const float* __restrict__ W2, unsigned short* W2hiT,
                       const float* __restrict__ a1s, const float* __restrict__ a1d,
                       unsigned short* W1aThi, unsigned short* W1aTlo,
                       int* cursor) {
    int i = blockIdx.x * 256 + threadIdx.x;
    if (i < 128 * 512) {
        int col = i & 511, k = i >> 9;
        W1hiT[col * 128 + k] = f2bf(W1[k * 512 + col]);
    } else if (i < 128 * 512 + 512 * 16) {
        int j = i - 128 * 512;
        int col = j & 15, k = j >> 4;
        W2hiT[col * 512 + k] = f2bf(W2[k * 16 + col]);
    } else if (i < 128 * 512 + 512 * 16 + 128 * 16) {
        int j = i - (128 * 512 + 512 * 16);
        int c16 = j & 15, k = j >> 4;
        int hd = c16 & 7;
        const float* av = (c16 < 8) ? a1s : a1d;
        float acc = 0.f;
#pragma unroll 8
        for (int c = 0; c < 64; c++)
            acc = fmaf(W1[k * 512 + hd * 64 + c], av[hd * 64 + c], acc);
        unsigned short h = f2bf(acc);
        W1aThi[c16 * 128 + k] = h;
        W1aTlo[c16 * 128 + k] = f2bf(acc - bf2f(h));
    } else {
        int j = i - (128 * 512 + 512 * 16 + 128 * 16);
        if (j < N_NODES) cursor[j] = 0;
    }
}

/* ---------------- merged: edge scatter-append (blocks < SCAT) + layer-1 GEMM ---------------- */
#define SCAT 256
__global__ __launch_bounds__(256) void k_sg1(const int* __restrict__ ei,
                                             int* __restrict__ cursor,
                                             int* __restrict__ colsrc,
                                             const float* __restrict__ x,
                                             const unsigned short* __restrict__ W1hiT,
                                             const unsigned short* __restrict__ W1aThi,
                                             const unsigned short* __restrict__ W1aTlo,
                                             unsigned short* __restrict__ h1b,
                                             float* __restrict__ al1s,
                                             float* __restrict__ al1d) {
    __shared__ unsigned short xs_hi[64 * 136];
    if (blockIdx.x < SCAT) {
        int gtid = blockIdx.x * 256 + threadIdx.x;
        for (int i = gtid; i < N_TOT; i += SCAT * 256) {
            int src, dst;
            if (i < N_EDGES) { src = ei[i]; dst = ei[N_EDGES + i]; }
            else             { src = dst = i - N_EDGES; }
            int pos = atomicAdd(&cursor[dst], 1);
            if (pos < CAP) colsrc[dst * CAP + pos] = src;
        }
        return;
    }
    const int t = threadIdx.x;
    const int rb = (blockIdx.x - SCAT) * 64;

#pragma unroll
    for (int i = 0; i < 8; i++) {
        int idx = t + 256 * i;           /* 2048 float4 total */
        int r = idx >> 5;                /* 32 float4 per row */
        int k = (idx & 31) * 4;
        int gr = rb + r;
        float4 v = make_float4(0.f, 0.f, 0.f, 0.f);
        if (gr < N_NODES) v = *reinterpret_cast<const float4*>(&x[gr * 128 + k]);
        ushort4 hi;
        hi.x = f2bf(v.x); hi.y = f2bf(v.y); hi.z = f2bf(v.z); hi.w = f2bf(v.w);
        *reinterpret_cast<ushort4*>(&xs_hi[r * 136 + k]) = hi;
    }
    __syncthreads();

    const int lane = t & 63;
    const int w = t >> 6;
    const int kbase = (lane >> 4) * 8;
    const int colloc = (w << 4) + (lane & 15);

#pragma unroll
    for (int pr = 0; pr < 4; pr++) {
        bf16x8 bhi[2][4];
#pragma unroll
        for (int si = 0; si < 2; si++) {
            int col = (pr * 2 + si) * 64 + colloc;
#pragma unroll
            for (int kc = 0; kc < 4; kc++)
                bhi[si][kc] = *reinterpret_cast<const bf16x8*>(&W1hiT[col * 128 + kc * 32 + kbase]);
        }
#pragma unroll
        for (int mt = 0; mt < 4; mt++) {
            const int arow = mt * 16 + (lane & 15);
            bf16x8 ah[4];
#pragma unroll
            for (int kc = 0; kc < 4; kc++)
                ah[kc] = *reinterpret_cast<const bf16x8*>(&xs_hi[arow * 136 + kc * 32 + kbase]);
#pragma unroll
            for (int si = 0; si < 2; si++) {
                f32x4 acc = {0.f, 0.f, 0.f, 0.f};
#pragma unroll
                for (int kc = 0; kc < 4; kc++)
                    acc = __builtin_amdgcn_mfma_f32_16x16x32_bf16(ah[kc], bhi[si][kc], acc, 0, 0, 0);
                const int col = (pr * 2 + si) * 64 + colloc;
                const int r0 = rb + mt * 16 + (lane >> 4) * 4;
#pragma unroll
                for (int r = 0; r < 4; r++) {
                    int row = r0 + r;
                    if (row < N_NODES) h1b[row * 512 + col] = f2bf(acc[r]);
                }
            }
        }
    }

    /* fused attention-half tile: wave w handles m-tile w, cols 0..15 of W1a (hi+lo) */
    {
        const int c16 = lane & 15;
        bf16x8 bh[4], bl[4];
#pragma unroll
        for (int kc = 0; kc < 4; kc++) {
            bh[kc] = *reinterpret_cast<const bf16x8*>(&W1aThi[c16 * 128 + kc * 32 + kbase]);
            bl[kc] = *reinterpret_cast<const bf16x8*>(&W1aTlo[c16 * 128 + kc * 32 + kbase]);
        }
        const int arow = (w << 4) + (lane & 15);
        f32x4 acc = {0.f, 0.f, 0.f, 0.f};
#pragma unroll
        for (int kc = 0; kc < 4; kc++) {
            bf16x8 ah = *reinterpret_cast<const bf16x8*>(&xs_hi[arow * 136 + kc * 32 + kbase]);
            acc = __builtin_amdgcn_mfma_f32_16x16x32_bf16(ah, bh[kc], acc, 0, 0, 0);
            acc = __builtin_amdgcn_mfma_f32_16x16x32_bf16(ah, bl[kc], acc, 0, 0, 0);
        }
        const int r0 = rb + (w << 4) + (lane >> 4) * 4;
#pragma unroll
        for (int r = 0; r < 4; r++) {
            int row = r0 + r;
            if (row < N_NODES) {
                if (c16 < 8) al1s[row * 8 + c16] = acc[r];
                else         al1d[row * 8 + (c16 - 8)] = acc[r];
            }
        }
    }
}

/* ---------------- FUSED Layer-1 aggregation + Layer-2 GEMM row + att2 halves ----------------
   One wave per dst node. After the edge loop the wave holds the full post-ELU
   512-ch row (8 fp32/lane): compute h2[n] = row @ W2 in-wave (bf16 W2hiT, L1-hot),
   xor-butterfly the 16 partial cols, emit h2b + al2s/al2d. h1a never materialized. */
__global__ __launch_bounds__(256) void k_agg1(const int* __restrict__ cursor,
                                              const int* __restrict__ colsrc,
                                              const float* __restrict__ al1s,
                                              const float* __restrict__ al1d,
                                              const unsigned short* __restrict__ h1b,
                                              const float* __restrict__ b1,
                                              const unsigned short* __restrict__ W2hiT,
                                              const float* __restrict__ a2s,
                                              const float* __restrict__ a2d,
                                              unsigned short* __restrict__ h2b,
                                              float* __restrict__ al2s,
                                              float* __restrict__ al2d) {
    __shared__ float pw[4][8 * 65];
    int wid = threadIdx.x >> 6;
    int lane = threadIdx.x & 63;
    int n = blockIdx.x * 4 + wid;
    if (n >= N_NODES) return;
    int cnt = min(cursor[n], CAP);
    const int eb = n * CAP;
    const float4 d0 = *reinterpret_cast<const float4*>(&al1d[n * 8]);
    const float4 d1 = *reinterpret_cast<const float4*>(&al1d[n * 8 + 4]);
    int hA = lane >> 4, hB = hA + 4;
    int cA = 4 * lane, cB = 256 + 4 * lane;
    f32x4 aA = {0.f, 0.f, 0.f, 0.f}, aB = {0.f, 0.f, 0.f, 0.f};
    float sA = 0.f, sB = 0.f;
    float* mypw = pw[wid];

    int s0 = 0;
    float p[8];
    if (lane < cnt) {
        s0 = colsrc[eb + lane];
        const float4 u0 = *reinterpret_cast<const float4*>(&al1s[s0 * 8]);
        const float4 u1 = *reinterpret_cast<const float4*>(&al1s[s0 * 8 + 4]);
        p[0] = __expf(fminf(lrelu(u0.x + d0.x), 60.f));
        p[1] = __expf(fminf(lrelu(u0.y + d0.y), 60.f));
        p[2] = __expf(fminf(lrelu(u0.z + d0.z), 60.f));
        p[3] = __expf(fminf(lrelu(u0.w + d0.w), 60.f));
        p[4] = __expf(fminf(lrelu(u1.x + d1.x), 60.f));
        p[5] = __expf(fminf(lrelu(u1.y + d1.y), 60.f));
        p[6] = __expf(fminf(lrelu(u1.z + d1.z), 60.f));
        p[7] = __expf(fminf(lrelu(u1.w + d1.w), 60.f));
    } else {
#pragma unroll
        for (int h = 0; h < 8; h++) p[h] = 0.f;
    }
#pragma unroll
    for (int h = 0; h < 8; h++) mypw[h * 65 + lane] = p[h];

    for (int j = 0; j < cnt; j++) {
        int s = __shfl(s0, j, 64);
        float wA = mypw[hA * 65 + j];
        float wB = mypw[hB * 65 + j];
        ushort4 hvA = *reinterpret_cast<const ushort4*>(&h1b[s * 512 + cA]);
        ushort4 hvB = *reinterpret_cast<const ushort4*>(&h1b[s * 512 + cB]);
        sA += wA; sB += wB;
        aA[0] = fmaf(wA, bf2f(hvA.x), aA[0]);
        aA[1] = fmaf(wA, bf2f(hvA.y), aA[1]);
        aA[2] = fmaf(wA, bf2f(hvA.z), aA[2]);
        aA[3] = fmaf(wA, bf2f(hvA.w), aA[3]);
        aB[0] = fmaf(wB, bf2f(hvB.x), aB[0]);
        aB[1] = fmaf(wB, bf2f(hvB.y), aB[1]);
        aB[2] = fmaf(wB, bf2f(hvB.z), aB[2]);
        aB[3] = fmaf(wB, bf2f(hvB.w), aB[3]);
    }
    float iA = 1.f / sA, iB = 1.f / sB;
    const float4 bA = *reinterpret_cast<const float4*>(&b1[cA]);
    const float4 bB = *reinterpret_cast<const float4*>(&b1[cB]);
    float vA[4], vB[4];
    vA[0] = aA[0] * iA + bA.x; vA[1] = aA[1] * iA + bA.y;
    vA[2] = aA[2] * iA + bA.z; vA[3] = aA[3] * iA + bA.w;
    vB[0] = aB[0] * iB + bB.x; vB[1] = aB[1] * iB + bB.y;
    vB[2] = aB[2] * iB + bB.z; vB[3] = aB[3] * iB + bB.w;
#pragma unroll
    for (int k = 0; k < 4; k++) {
        vA[k] = vA[k] > 0.f ? vA[k] : __expf(vA[k]) - 1.f;
        vB[k] = vB[k] > 0.f ? vB[k] : __expf(vB[k]) - 1.f;
    }

    /* layer-2 GEMM row: lane covers channels [cA,cA+4) and [cB,cB+4) */
    float p2[16];
#pragma unroll
    for (int c = 0; c < 16; c++) {
        ushort4 wA = *reinterpret_cast<const ushort4*>(&W2hiT[c * 512 + cA]);
        ushort4 wB = *reinterpret_cast<const ushort4*>(&W2hiT[c * 512 + cB]);
        float s2 = vA[0] * bf2f(wA.x) + vA[1] * bf2f(wA.y)
                 + vA[2] * bf2f(wA.z) + vA[3] * bf2f(wA.w)
                 + vB[0] * bf2f(wB.x) + vB[1] * bf2f(wB.y)
                 + vB[2] * bf2f(wB.z) + vB[3] * bf2f(wB.w);
        p2[c] = s2;
    }
#pragma unroll
    for (int off = 1; off < 64; off <<= 1) {
#pragma unroll
        for (int c = 0; c < 16; c++) p2[c] += __shfl_xor(p2[c], off, 64);
    }
    /* all lanes now hold the full h2 row */
    float ps = 0.f, pd = 0.f;
#pragma unroll
    for (int c = 0; c < 16; c++) {
        ps = fmaf(p2[c], a2s[c], ps);
        pd = fmaf(p2[c], a2d[c], pd);
    }
    if (lane == 0) { al2s[n] = ps; al2d[n] = pd; }
    if (lane < 16) {
        float hv = p2[0];
#pragma unroll
        for (int c = 1; c < 16; c++) hv = (lane == c) ? p2[c] : hv;
        h2b[n * 16 + lane] = f2bf(hv);
    }
}

/* ---------------- Layer 2 aggregation -> out (bf16 h2, 2-deep unrolled) ---------------- */
__global__ __launch_bounds__(256) void k_agg2(const int* __restrict__ cursor,
                                              const int* __restrict__ colsrc,
                                              const float* __restrict__ al2s,
                                              const float* __restrict__ al2d,
                                              const unsigned short* __restrict__ h2b,
                                              const float* __restrict__ b2,
                                              float* __restrict__ out) {
    int wv = threadIdx.x >> 6, lane = threadIdx.x & 63;
    int n = blockIdx.x * 4 + wv;
    if (n >= N_NODES) return;
    int cnt = min(cursor[n], CAP);
    const int eb = n * CAP;
    float ald = al2d[n];
    int c = lane & 15, q = lane >> 4;
    float acc = 0.f, smL = 0.f;
    int e = q;
    for (; e + 4 < cnt; e += 8) {
        int s0 = colsrc[eb + e];
        int s1 = colsrc[eb + e + 4];
        float w0 = __expf(fminf(lrelu(al2s[s0] + ald), 60.f));
        float w1 = __expf(fminf(lrelu(al2s[s1] + ald), 60.f));
        unsigned short v0 = h2b[s0 * 16 + c];
        unsigned short v1 = h2b[s1 * 16 + c];
        smL += w0 + w1;
        acc = fmaf(w0, bf2f(v0), acc);
        acc = fmaf(w1, bf2f(v1), acc);
    }
    for (; e < cnt; e += 4) {
        int s = colsrc[eb + e];
        float w = __expf(fminf(lrelu(al2s[s] + ald), 60.f));
        smL += w;
        acc = fmaf(w, bf2f(h2b[s * 16 + c]), acc);
    }
    acc += __shfl_xor(acc, 16, 64); smL += __shfl_xor(smL, 16, 64);
    acc += __shfl_xor(acc, 32, 64); smL += __shfl_xor(smL, 32, 64);
    if (q == 0) out[n * 16 + c] = acc / smL + b2[c];
}

/* ---------------- launch ---------------- */
extern "C" void kernel_launch(void* const* d_in, const int* in_sizes, int n_in,
                              void* d_out, int out_size, void* d_ws, size_t ws_size,
                              hipStream_t stream) {
    const float* x   = (const float*)d_in[0];
    const int*   ei  = (const int*)d_in[1];
    const float* W1  = (const float*)d_in[2];
    const float* a1s = (const float*)d_in[3];
    const float* a1d = (const float*)d_in[4];
    const float* b1  = (const float*)d_in[5];
    const float* W2  = (const float*)d_in[6];
    const float* a2s = (const float*)d_in[7];
    const float* a2d = (const float*)d_in[8];
    const float* b2  = (const float*)d_in[9];
    float* out = (float*)d_out;

    char* ws = (char*)d_ws;
    unsigned short* h1b = (unsigned short*)(ws + 0);            /* N*512 bf16 = 51.2 MB */
    unsigned short* h2b = (unsigned short*)(ws + 51200000);     /* N*16 bf16 = 1.6 MB */
    float* al1s = (float*)(ws + 54400000);     /* N*8 */
    float* al1d = (float*)(ws + 56000000);     /* N*8 */
    float* al2s = (float*)(ws + 57600000);     /* N */
    float* al2d = (float*)(ws + 57800000);     /* N */
    int* cursor = (int*)(ws + 58000000);       /* N ints */
    int* colsrc = (int*)(ws + 58200000);       /* N*CAP ints = 12.8 MB */
    unsigned short* W1hiT  = (unsigned short*)(ws + 71000000);  /* 512x128 bf16 */
    unsigned short* W2hiT  = (unsigned short*)(ws + 71136000);  /* 16x512 bf16 */
    unsigned short* W1aThi = (unsigned short*)(ws + 71152384);  /* 16x128 bf16 */
    unsigned short* W1aTlo = (unsigned short*)(ws + 71156480);

    /* init: weight prep + cursor zero */
    k_init<<<492, 256, 0, stream>>>(W1, W1hiT, W2, W2hiT, a1s, a1d, W1aThi, W1aTlo, cursor);

    /* scatter-append + layer-1 GEMM (merged) */
    k_sg1<<<SCAT + (N_NODES + 63) / 64, 256, 0, stream>>>(ei, cursor, colsrc, x,
                                                          W1hiT, W1aThi, W1aTlo,
                                                          h1b, al1s, al1d);

    /* fused: layer-1 aggregation + layer-2 GEMM row + att2 halves */
    k_agg1<<<(N_NODES + 3) / 4, 256, 0, stream>>>(cursor, colsrc, al1s, al1d, h1b, b1,
                                                  W2hiT, a2s, a2d, h2b, al2s, al2d);

    /* layer 2 aggregation */
    k_agg2<<<(N_NODES + 3) / 4, 256, 0, stream>>>(cursor, colsrc, al2s, al2d, h2b, b2, out);
}